// Round 1
// baseline (1214.740 us; speedup 1.0000x reference)
//
#include <hip/hip_runtime.h>
#include <hip/hip_bf16.h>

#define N_IN   200000
#define N_OUT  100000
#define NEDGE  1600000
#define CIN    64
#define KS     9
#define C_A    96
#define C_B    32
#define C_TOT  128
#define EPSV   1e-8f

#define TROWS  16            // output rows per block (MFMA M)
#define KC     576           // K*CIN contraction length
#define BINSTRIDE 580        // 576 + 4 pad: breaks 32-bank aliasing across rows
#define KSTEPS 18            // 576 / 32
#define NTILES 8             // 128 couts / 16
#define WPACK_ELEMS (NTILES * KSTEPS * 64 * 8)   // 73728 bf16
#define WS_ROWBYTES 400128                        // (N_OUT+1)*4 rounded to 128

typedef __attribute__((ext_vector_type(8))) short short8;
typedef __attribute__((ext_vector_type(4))) float f32x4;

__device__ __forceinline__ short f2bf(float f) {
    __hip_bfloat16 h = __float2bfloat16(f);
    return __builtin_bit_cast(short, h);
}

// CSR row offsets from sorted out-index. row[o] = first edge with out>=o; row[N_OUT]=E.
__global__ void build_rows(const int* __restrict__ oidx, int* __restrict__ row) {
    int e = blockIdx.x * blockDim.x + threadIdx.x;
    if (e >= NEDGE) return;
    int cur  = oidx[e];
    int prev = (e == 0) ? -1 : oidx[e - 1];
    for (int o = prev + 1; o <= cur; ++o) row[o] = e;
    if (e == NEDGE - 1)
        for (int o = cur + 1; o <= N_OUT; ++o) row[o] = NEDGE;
}

// Pack W_a|W_b into bf16 MFMA B-fragment order:
// Wp[((n*18+s)*64 + lane)*8 + j] = Wcat[kc = s*32+(lane>>4)*8+j][cout = n*16+(lane&15)]
__global__ void pack_w(const float* __restrict__ Wa, const float* __restrict__ Wb,
                       __hip_bfloat16* __restrict__ Wp) {
    int f = blockIdx.x * blockDim.x + threadIdx.x;
    if (f >= WPACK_ELEMS) return;
    int j = f & 7;
    int l = (f >> 3) & 63;
    int s = (f >> 9) % KSTEPS;
    int n = f / (512 * KSTEPS);
    int kc   = s * 32 + (l >> 4) * 8 + j;
    int cout = n * 16 + (l & 15);
    float v = (cout < C_A) ? Wa[kc * C_A + cout] : Wb[kc * C_B + (cout - C_A)];
    Wp[f] = __float2bfloat16(v);
}

__global__ __launch_bounds__(512, 4)
void fused_kernel(const float* __restrict__ feats,
                  const float* __restrict__ importance,
                  const float* __restrict__ b_a,
                  const float* __restrict__ b_b,
                  const int* __restrict__ nbr_idx,
                  const int* __restrict__ k_idx,
                  const int* __restrict__ out_idx,
                  const int* __restrict__ row_start,
                  const __hip_bfloat16* __restrict__ Wp,
                  float* __restrict__ out) {
    __shared__ float bin_a[TROWS][BINSTRIDE];
    __shared__ float bin_b[TROWS][BINSTRIDE];
    __shared__ float imp_s[TROWS];

    const int tid  = threadIdx.x;
    const int wave = tid >> 6;
    const int lane = tid & 63;
    const int o0   = blockIdx.x * TROWS;

    // zero LDS
    for (int i = tid; i < TROWS * BINSTRIDE; i += 512) {
        (&bin_a[0][0])[i] = 0.f;
        (&bin_b[0][0])[i] = 0.f;
    }
    if (tid < TROWS) imp_s[tid] = 0.f;
    __syncthreads();

    const int e_start = row_start[o0];
    const int e_end   = row_start[o0 + TROWS];
    const int ne      = e_end - e_start;

    // Phase 1: bin edges. One wave per edge (lane = channel), 4 edges per wave per round.
    for (int base = wave * 4; base < ne; base += 32) {
        int cnt = ne - base; if (cnt > 4) cnt = 4;
        int nbr[4], kk[4], tt[4];
        float gv[4], iv[4];
        #pragma unroll
        for (int u = 0; u < 4; ++u) {
            if (u < cnt) {
                int e = e_start + base + u;
                nbr[u] = nbr_idx[e];
                kk[u]  = k_idx[e];
                tt[u]  = out_idx[e] - o0;
            }
        }
        #pragma unroll
        for (int u = 0; u < 4; ++u)
            if (u < cnt) gv[u] = feats[nbr[u] * CIN + lane];
        #pragma unroll
        for (int u = 0; u < 4; ++u)
            if (u < cnt) iv[u] = importance[nbr[u]];
        #pragma unroll
        for (int u = 0; u < 4; ++u) {
            if (u < cnt) {
                atomicAdd(&bin_a[tt[u]][kk[u] * CIN + lane], gv[u]);
                atomicAdd(&bin_b[tt[u]][kk[u] * CIN + lane], gv[u] * iv[u]);
                if (lane == 0) atomicAdd(&imp_s[tt[u]], iv[u]);
            }
        }
    }
    __syncthreads();

    // Phase 2: 8 waves, wave w computes 16x16 output tile (couts w*16..w*16+15).
    // Waves 0-5 contract bin_a (C_A=96), waves 6-7 contract bin_b (C_B=32).
    const float* binp = (wave < 6) ? &bin_a[0][0] : &bin_b[0][0];
    const int mrow = lane & 15;   // A-fragment M index
    const int kgrp = lane >> 4;   // K-chunk select
    f32x4 acc = {0.f, 0.f, 0.f, 0.f};
    const short8* wp = reinterpret_cast<const short8*>(Wp) + wave * KSTEPS * 64 + lane;
    const float* ap0 = binp + mrow * BINSTRIDE + kgrp * 8;
    #pragma unroll
    for (int s = 0; s < KSTEPS; ++s) {
        const f32x4* ap = reinterpret_cast<const f32x4*>(ap0 + s * 32);
        f32x4 x0 = ap[0];
        f32x4 x1 = ap[1];
        short8 a;
        a[0] = f2bf(x0[0]); a[1] = f2bf(x0[1]); a[2] = f2bf(x0[2]); a[3] = f2bf(x0[3]);
        a[4] = f2bf(x1[0]); a[5] = f2bf(x1[1]); a[6] = f2bf(x1[2]); a[7] = f2bf(x1[3]);
        short8 b = wp[s * 64];
        acc = __builtin_amdgcn_mfma_f32_16x16x32_bf16(a, b, acc, 0, 0, 0);
    }

    // Epilogue: bias + (importance norm for B path) + relu; C/D layout col=lane&15, row=kgrp*4+j
    int cout = wave * 16 + mrow;
    float bias = (wave < 6) ? b_a[cout] : b_b[cout - C_A];
    #pragma unroll
    for (int j = 0; j < 4; ++j) {
        int t = kgrp * 4 + j;
        float y = acc[j];
        if (wave >= 6) y = y / fmaxf(imp_s[t], EPSV);
        y += bias;
        y = fmaxf(y, 0.f);
        out[(long)(o0 + t) * C_TOT + cout] = y;
    }
    if (wave == 7 && lane < TROWS)
        out[(long)N_OUT * C_TOT + o0 + lane] = imp_s[lane];
}

extern "C" void kernel_launch(void* const* d_in, const int* in_sizes, int n_in,
                              void* d_out, int out_size, void* d_ws, size_t ws_size,
                              hipStream_t stream) {
    const float* feats      = (const float*)d_in[0];
    const float* importance = (const float*)d_in[1];
    const float* W_a        = (const float*)d_in[2];
    const float* b_a        = (const float*)d_in[3];
    const float* W_b        = (const float*)d_in[4];
    const float* b_b        = (const float*)d_in[5];
    const int*   nbr        = (const int*)d_in[6];
    const int*   kidx       = (const int*)d_in[7];
    const int*   oidx       = (const int*)d_in[8];
    float* out = (float*)d_out;

    int* row_start = (int*)d_ws;
    __hip_bfloat16* Wp = (__hip_bfloat16*)((char*)d_ws + WS_ROWBYTES);

    hipLaunchKernelGGL(build_rows, dim3((NEDGE + 255) / 256), dim3(256), 0, stream, oidx, row_start);
    hipLaunchKernelGGL(pack_w, dim3((WPACK_ELEMS + 255) / 256), dim3(256), 0, stream, W_a, W_b, Wp);
    hipLaunchKernelGGL(fused_kernel, dim3(N_OUT / TROWS), dim3(512), 0, stream,
                       feats, importance, b_a, b_b, nbr, kidx, oidx, row_start, Wp, out);
}